// Round 3
// baseline (82.256 us; speedup 1.0000x reference)
//
#include <hip/hip_runtime.h>

#define SEQ   2048
#define EMB   128
#define NH    16
#define DKW   8
#define NB    2
#define QBLK  128            // query rows per block
#define NCHUNK 4             // t-chunks (waves-level split of the key loop)
#define TCHUNK (SEQ / NCHUNK)          // 512
#define K1_THREADS (QBLK * NCHUNK)     // 512
#define NQT   (SEQ / QBLK)   // 16
#define NBH   (NB * NH)      // 32

// Kernel 1: per (b, h, q-tile). Stage K = cos(x+theta) for the whole head in
// LDS (64 KiB). thread = (chunk, row): each of the 4 chunk-groups processes a
// disjoint 512-token slice of the key stream for its query row (softmax needs
// no max: |score| <= sqrt(8)), then partials (l, sum p*k) reduce through LDS.
__global__ __launch_bounds__(K1_THREADS, 4) void qattn_kernel(const float* __restrict__ x,
                                                              const float* __restrict__ theta,
                                                              float* __restrict__ ws) {
    __shared__ float4 K4[SEQ * 2];  // K4[2t], K4[2t+1] = 8 floats of token t

    const int tid = threadIdx.x;
    const int bid = blockIdx.x;
    const int bh  = bid % NBH;   // (b,h)
    const int qt  = bid / NBH;   // q tile
    const int b   = bh >> 4;
    const int h   = bh & 15;

    float th[DKW];
#pragma unroll
    for (int d = 0; d < DKW; ++d) th[d] = theta[d];

    // token t, head h occupies float4 slots (t*32 + h*2) and (+1) of x[b]
    const float4* x4 = (const float4*)x + (size_t)b * SEQ * (EMB / 4) + h * 2;

    for (int t = tid; t < SEQ; t += K1_THREADS) {
        float4 lo = x4[(size_t)t * (EMB / 4)];
        float4 hi = x4[(size_t)t * (EMB / 4) + 1];
        float4 klo, khi;
        klo.x = __cosf(lo.x + th[0]);
        klo.y = __cosf(lo.y + th[1]);
        klo.z = __cosf(lo.z + th[2]);
        klo.w = __cosf(lo.w + th[3]);
        khi.x = __cosf(hi.x + th[4]);
        khi.y = __cosf(hi.y + th[5]);
        khi.z = __cosf(hi.z + th[6]);
        khi.w = __cosf(hi.w + th[7]);
        K4[t * 2]     = klo;
        K4[t * 2 + 1] = khi;
    }
    __syncthreads();

    const int row   = tid & (QBLK - 1);
    const int chunk = tid >> 7;           // 0..3
    const int qrow  = qt * QBLK + row;

    // pre-scale q: exp((q.k)/sqrt(8)) = exp2((q*C).k), C = log2(e)/sqrt(8)
    const float C = 0.35355339059327373f * 1.4426950408889634f;
    float4 qlo = K4[qrow * 2];
    float4 qhi = K4[qrow * 2 + 1];
    qlo.x *= C; qlo.y *= C; qlo.z *= C; qlo.w *= C;
    qhi.x *= C; qhi.y *= C; qhi.z *= C; qhi.w *= C;

    float  l  = 0.0f;
    float4 a0 = make_float4(0.f, 0.f, 0.f, 0.f);
    float4 a1 = make_float4(0.f, 0.f, 0.f, 0.f);

    const float4* Kp = &K4[chunk * TCHUNK * 2];
#pragma unroll 8
    for (int t = 0; t < TCHUNK; ++t) {
        float4 klo = Kp[t * 2];
        float4 khi = Kp[t * 2 + 1];
        float s = qlo.x * klo.x;
        s = fmaf(qlo.y, klo.y, s);
        s = fmaf(qlo.z, klo.z, s);
        s = fmaf(qlo.w, klo.w, s);
        s = fmaf(qhi.x, khi.x, s);
        s = fmaf(qhi.y, khi.y, s);
        s = fmaf(qhi.z, khi.z, s);
        s = fmaf(qhi.w, khi.w, s);
        float p = __builtin_exp2f(s);
        l += p;
        a0.x = fmaf(p, klo.x, a0.x);
        a0.y = fmaf(p, klo.y, a0.y);
        a0.z = fmaf(p, klo.z, a0.z);
        a0.w = fmaf(p, klo.w, a0.w);
        a1.x = fmaf(p, khi.x, a1.x);
        a1.y = fmaf(p, khi.y, a1.y);
        a1.z = fmaf(p, khi.z, a1.z);
        a1.w = fmaf(p, khi.w, a1.w);
    }

    // ---- reduce partials across the 4 chunk-groups (reuse K4 LDS) ----
    __syncthreads();                       // all K4 reads done
    float* red = (float*)K4;               // (NCHUNK-1)*QBLK*9 floats = 13.5 KB
    if (chunk != 0) {
        int base = (tid - QBLK) * 9;       // stride 9: conflict-free (gcd(9,32)=1)
        red[base + 0] = a0.x; red[base + 1] = a0.y;
        red[base + 2] = a0.z; red[base + 3] = a0.w;
        red[base + 4] = a1.x; red[base + 5] = a1.y;
        red[base + 6] = a1.z; red[base + 7] = a1.w;
        red[base + 8] = l;
    }
    __syncthreads();
    if (chunk == 0) {
#pragma unroll
        for (int c = 0; c < NCHUNK - 1; ++c) {
            int base = (c * QBLK + row) * 9;
            a0.x += red[base + 0]; a0.y += red[base + 1];
            a0.z += red[base + 2]; a0.w += red[base + 3];
            a1.x += red[base + 4]; a1.y += red[base + 5];
            a1.z += red[base + 6]; a1.w += red[base + 7];
            l    += red[base + 8];
        }
        float inv = 1.0f / l;
        a0.x *= inv; a0.y *= inv; a0.z *= inv; a0.w *= inv;
        a1.x *= inv; a1.y *= inv; a1.z *= inv; a1.w *= inv;

        float4* o = (float4*)ws + ((size_t)(b * SEQ + qrow)) * (EMB / 4) + h * 2;
        o[0] = a0;
        o[1] = a1;
    }
}

// Kernel 2: out[r][e] = sum_k ws[r][k] * W[e][k]   (r = 0..4095, e,k = 0..127)
#define K2_ROWS 16
#define K2_THREADS 512
#define WT_STRIDE 132

__global__ __launch_bounds__(K2_THREADS) void combine_kernel(const float* __restrict__ ws,
                                                             const float* __restrict__ W,
                                                             float* __restrict__ out) {
    __shared__ float Wt[128 * WT_STRIDE];   // Wt[k*132 + e] = W[e][k]
    __shared__ float Xs[K2_ROWS * 128];

    const int tid   = threadIdx.x;
    const int rbase = blockIdx.x * K2_ROWS;

    for (int i = tid; i < 128 * 128; i += K2_THREADS) {
        int e = i >> 7, k = i & 127;        // coalesced global read
        Wt[k * WT_STRIDE + e] = W[i];
    }
    for (int i = tid; i < K2_ROWS * 128; i += K2_THREADS) {
        Xs[i] = ws[(size_t)rbase * 128 + i];
    }
    __syncthreads();

    const int r = tid >> 5;   // 0..15 (row within tile)
    const int g = tid & 31;   // column group: outputs e = 4g..4g+3
    float4 acc = make_float4(0.f, 0.f, 0.f, 0.f);

    const float4* X4 = (const float4*)&Xs[r * 128];
#pragma unroll
    for (int kc = 0; kc < 32; ++kc) {
        float4 x4 = X4[kc];  // broadcast within row group
#pragma unroll
        for (int j = 0; j < 4; ++j) {
            int k = kc * 4 + j;
            float4 w = *(const float4*)&Wt[k * WT_STRIDE + g * 4];
            float xv = (j == 0) ? x4.x : (j == 1) ? x4.y : (j == 2) ? x4.z : x4.w;
            acc.x = fmaf(xv, w.x, acc.x);
            acc.y = fmaf(xv, w.y, acc.y);
            acc.z = fmaf(xv, w.z, acc.z);
            acc.w = fmaf(xv, w.w, acc.w);
        }
    }

    ((float4*)out)[(size_t)(rbase + r) * 32 + g] = acc;
}

extern "C" void kernel_launch(void* const* d_in, const int* in_sizes, int n_in,
                              void* d_out, int out_size, void* d_ws, size_t ws_size,
                              hipStream_t stream) {
    const float* x     = (const float*)d_in[0];
    const float* theta = (const float*)d_in[1];
    const float* W     = (const float*)d_in[2];
    float* out = (float*)d_out;
    float* ws  = (float*)d_ws;   // needs B*S*E*4 = 2 MiB

    qattn_kernel<<<NBH * NQT, K1_THREADS, 0, stream>>>(x, theta, ws);
    combine_kernel<<<(NB * SEQ) / K2_ROWS, K2_THREADS, 0, stream>>>(ws, W, out);
}

// Round 4
// 82.216 us; speedup vs baseline: 1.0005x; 1.0005x over previous
//
#include <hip/hip_runtime.h>

#define SEQ   2048
#define EMB   128
#define NH    16
#define DKW   8
#define NB    2
#define QBLK  128            // query rows per block
#define NCHUNK 4             // t-chunks (waves-level split of the key loop)
#define TCHUNK (SEQ / NCHUNK)          // 512
#define K1_THREADS (QBLK * NCHUNK)     // 512
#define NQT   (SEQ / QBLK)   // 16
#define NBH   (NB * NH)      // 32

// Kernel 1: per (b, h, q-tile). Stage K = cos(x+theta) for the whole head in
// LDS (64 KiB). thread = (chunk, row): each of the 4 chunk-groups processes a
// disjoint 512-token slice of the key stream for its query row (softmax needs
// no max: |score| <= sqrt(8)), then partials (l, sum p*k) reduce through LDS.
__global__ __launch_bounds__(K1_THREADS, 4) void qattn_kernel(const float* __restrict__ x,
                                                              const float* __restrict__ theta,
                                                              float* __restrict__ ws) {
    __shared__ float4 K4[SEQ * 2];  // K4[2t], K4[2t+1] = 8 floats of token t

    const int tid = threadIdx.x;
    const int bid = blockIdx.x;
    const int bh  = bid % NBH;   // (b,h)
    const int qt  = bid / NBH;   // q tile
    const int b   = bh >> 4;
    const int h   = bh & 15;

    float th[DKW];
#pragma unroll
    for (int d = 0; d < DKW; ++d) th[d] = theta[d];

    // token t, head h occupies float4 slots (t*32 + h*2) and (+1) of x[b]
    const float4* x4 = (const float4*)x + (size_t)b * SEQ * (EMB / 4) + h * 2;

    for (int t = tid; t < SEQ; t += K1_THREADS) {
        float4 lo = x4[(size_t)t * (EMB / 4)];
        float4 hi = x4[(size_t)t * (EMB / 4) + 1];
        float4 klo, khi;
        klo.x = __cosf(lo.x + th[0]);
        klo.y = __cosf(lo.y + th[1]);
        klo.z = __cosf(lo.z + th[2]);
        klo.w = __cosf(lo.w + th[3]);
        khi.x = __cosf(hi.x + th[4]);
        khi.y = __cosf(hi.y + th[5]);
        khi.z = __cosf(hi.z + th[6]);
        khi.w = __cosf(hi.w + th[7]);
        K4[t * 2]     = klo;
        K4[t * 2 + 1] = khi;
    }
    __syncthreads();

    const int row   = tid & (QBLK - 1);
    const int chunk = tid >> 7;           // 0..3
    const int qrow  = qt * QBLK + row;

    // pre-scale q: exp((q.k)/sqrt(8)) = exp2((q*C).k), C = log2(e)/sqrt(8)
    const float C = 0.35355339059327373f * 1.4426950408889634f;
    float4 qlo = K4[qrow * 2];
    float4 qhi = K4[qrow * 2 + 1];
    qlo.x *= C; qlo.y *= C; qlo.z *= C; qlo.w *= C;
    qhi.x *= C; qhi.y *= C; qhi.z *= C; qhi.w *= C;

    float  l  = 0.0f;
    float4 a0 = make_float4(0.f, 0.f, 0.f, 0.f);
    float4 a1 = make_float4(0.f, 0.f, 0.f, 0.f);

    const float4* Kp = &K4[chunk * TCHUNK * 2];
#pragma unroll 8
    for (int t = 0; t < TCHUNK; ++t) {
        float4 klo = Kp[t * 2];
        float4 khi = Kp[t * 2 + 1];
        float s = qlo.x * klo.x;
        s = fmaf(qlo.y, klo.y, s);
        s = fmaf(qlo.z, klo.z, s);
        s = fmaf(qlo.w, klo.w, s);
        s = fmaf(qhi.x, khi.x, s);
        s = fmaf(qhi.y, khi.y, s);
        s = fmaf(qhi.z, khi.z, s);
        s = fmaf(qhi.w, khi.w, s);
        float p = __builtin_exp2f(s);
        l += p;
        a0.x = fmaf(p, klo.x, a0.x);
        a0.y = fmaf(p, klo.y, a0.y);
        a0.z = fmaf(p, klo.z, a0.z);
        a0.w = fmaf(p, klo.w, a0.w);
        a1.x = fmaf(p, khi.x, a1.x);
        a1.y = fmaf(p, khi.y, a1.y);
        a1.z = fmaf(p, khi.z, a1.z);
        a1.w = fmaf(p, khi.w, a1.w);
    }

    // ---- reduce partials across the 4 chunk-groups (reuse K4 LDS) ----
    __syncthreads();                       // all K4 reads done
    float* red = (float*)K4;               // (NCHUNK-1)*QBLK*9 floats = 13.5 KB
    if (chunk != 0) {
        int base = (tid - QBLK) * 9;       // stride 9: conflict-free (gcd(9,32)=1)
        red[base + 0] = a0.x; red[base + 1] = a0.y;
        red[base + 2] = a0.z; red[base + 3] = a0.w;
        red[base + 4] = a1.x; red[base + 5] = a1.y;
        red[base + 6] = a1.z; red[base + 7] = a1.w;
        red[base + 8] = l;
    }
    __syncthreads();
    if (chunk == 0) {
#pragma unroll
        for (int c = 0; c < NCHUNK - 1; ++c) {
            int base = (c * QBLK + row) * 9;
            a0.x += red[base + 0]; a0.y += red[base + 1];
            a0.z += red[base + 2]; a0.w += red[base + 3];
            a1.x += red[base + 4]; a1.y += red[base + 5];
            a1.z += red[base + 6]; a1.w += red[base + 7];
            l    += red[base + 8];
        }
        float inv = 1.0f / l;
        a0.x *= inv; a0.y *= inv; a0.z *= inv; a0.w *= inv;
        a1.x *= inv; a1.y *= inv; a1.z *= inv; a1.w *= inv;

        float4* o = (float4*)ws + ((size_t)(b * SEQ + qrow)) * (EMB / 4) + h * 2;
        o[0] = a0;
        o[1] = a1;
    }
}

// Kernel 2: out[r][e] = sum_k ws[r][k] * W[e][k]   (r = 0..4095, e,k = 0..127)
#define K2_ROWS 16
#define K2_THREADS 512
#define WT_STRIDE 132

__global__ __launch_bounds__(K2_THREADS) void combine_kernel(const float* __restrict__ ws,
                                                             const float* __restrict__ W,
                                                             float* __restrict__ out) {
    __shared__ float Wt[128 * WT_STRIDE];   // Wt[k*132 + e] = W[e][k]
    __shared__ float Xs[K2_ROWS * 128];

    const int tid   = threadIdx.x;
    const int rbase = blockIdx.x * K2_ROWS;

    for (int i = tid; i < 128 * 128; i += K2_THREADS) {
        int e = i >> 7, k = i & 127;        // coalesced global read
        Wt[k * WT_STRIDE + e] = W[i];
    }
    for (int i = tid; i < K2_ROWS * 128; i += K2_THREADS) {
        Xs[i] = ws[(size_t)rbase * 128 + i];
    }
    __syncthreads();

    const int r = tid >> 5;   // 0..15 (row within tile)
    const int g = tid & 31;   // column group: outputs e = 4g..4g+3
    float4 acc = make_float4(0.f, 0.f, 0.f, 0.f);

    const float4* X4 = (const float4*)&Xs[r * 128];
#pragma unroll
    for (int kc = 0; kc < 32; ++kc) {
        float4 x4 = X4[kc];  // broadcast within row group
#pragma unroll
        for (int j = 0; j < 4; ++j) {
            int k = kc * 4 + j;
            float4 w = *(const float4*)&Wt[k * WT_STRIDE + g * 4];
            float xv = (j == 0) ? x4.x : (j == 1) ? x4.y : (j == 2) ? x4.z : x4.w;
            acc.x = fmaf(xv, w.x, acc.x);
            acc.y = fmaf(xv, w.y, acc.y);
            acc.z = fmaf(xv, w.z, acc.z);
            acc.w = fmaf(xv, w.w, acc.w);
        }
    }

    ((float4*)out)[(size_t)(rbase + r) * 32 + g] = acc;
}

extern "C" void kernel_launch(void* const* d_in, const int* in_sizes, int n_in,
                              void* d_out, int out_size, void* d_ws, size_t ws_size,
                              hipStream_t stream) {
    const float* x     = (const float*)d_in[0];
    const float* theta = (const float*)d_in[1];
    const float* W     = (const float*)d_in[2];
    float* out = (float*)d_out;
    float* ws  = (float*)d_ws;   // needs B*S*E*4 = 2 MiB

    qattn_kernel<<<NBH * NQT, K1_THREADS, 0, stream>>>(x, theta, ws);
    combine_kernel<<<(NB * SEQ) / K2_ROWS, K2_THREADS, 0, stream>>>(ws, W, out);
}

// Round 5
// 82.139 us; speedup vs baseline: 1.0014x; 1.0009x over previous
//
#include <hip/hip_runtime.h>

#define SEQ   2048
#define EMB   128
#define NH    16
#define DKW   8
#define NB    2
#define QBLK  128            // query rows per block
#define NCHUNK 4             // t-chunks (waves-level split of the key loop)
#define TCHUNK (SEQ / NCHUNK)          // 512
#define K1_THREADS (QBLK * NCHUNK)     // 512
#define NQT   (SEQ / QBLK)   // 16
#define NBH   (NB * NH)      // 32

// Kernel 1: per (b, h, q-tile). Stage K = cos(x+theta) for the whole head in
// LDS (64 KiB). thread = (chunk, row): each of the 4 chunk-groups processes a
// disjoint 512-token slice of the key stream for its query row (softmax needs
// no max: |score| <= sqrt(8)), then partials (l, sum p*k) reduce through LDS.
__global__ __launch_bounds__(K1_THREADS, 4) void qattn_kernel(const float* __restrict__ x,
                                                              const float* __restrict__ theta,
                                                              float* __restrict__ ws) {
    __shared__ float4 K4[SEQ * 2];  // K4[2t], K4[2t+1] = 8 floats of token t

    const int tid = threadIdx.x;
    const int bid = blockIdx.x;
    const int bh  = bid % NBH;   // (b,h)
    const int qt  = bid / NBH;   // q tile
    const int b   = bh >> 4;
    const int h   = bh & 15;

    float th[DKW];
#pragma unroll
    for (int d = 0; d < DKW; ++d) th[d] = theta[d];

    // token t, head h occupies float4 slots (t*32 + h*2) and (+1) of x[b]
    const float4* x4 = (const float4*)x + (size_t)b * SEQ * (EMB / 4) + h * 2;

    for (int t = tid; t < SEQ; t += K1_THREADS) {
        float4 lo = x4[(size_t)t * (EMB / 4)];
        float4 hi = x4[(size_t)t * (EMB / 4) + 1];
        float4 klo, khi;
        klo.x = __cosf(lo.x + th[0]);
        klo.y = __cosf(lo.y + th[1]);
        klo.z = __cosf(lo.z + th[2]);
        klo.w = __cosf(lo.w + th[3]);
        khi.x = __cosf(hi.x + th[4]);
        khi.y = __cosf(hi.y + th[5]);
        khi.z = __cosf(hi.z + th[6]);
        khi.w = __cosf(hi.w + th[7]);
        K4[t * 2]     = klo;
        K4[t * 2 + 1] = khi;
    }
    __syncthreads();

    const int row   = tid & (QBLK - 1);
    const int chunk = tid >> 7;           // 0..3
    const int qrow  = qt * QBLK + row;

    // pre-scale q: exp((q.k)/sqrt(8)) = exp2((q*C).k), C = log2(e)/sqrt(8)
    const float C = 0.35355339059327373f * 1.4426950408889634f;
    float4 qlo = K4[qrow * 2];
    float4 qhi = K4[qrow * 2 + 1];
    qlo.x *= C; qlo.y *= C; qlo.z *= C; qlo.w *= C;
    qhi.x *= C; qhi.y *= C; qhi.z *= C; qhi.w *= C;

    float  l  = 0.0f;
    float4 a0 = make_float4(0.f, 0.f, 0.f, 0.f);
    float4 a1 = make_float4(0.f, 0.f, 0.f, 0.f);

    const float4* Kp = &K4[chunk * TCHUNK * 2];
#pragma unroll 8
    for (int t = 0; t < TCHUNK; ++t) {
        float4 klo = Kp[t * 2];
        float4 khi = Kp[t * 2 + 1];
        float s = qlo.x * klo.x;
        s = fmaf(qlo.y, klo.y, s);
        s = fmaf(qlo.z, klo.z, s);
        s = fmaf(qlo.w, klo.w, s);
        s = fmaf(qhi.x, khi.x, s);
        s = fmaf(qhi.y, khi.y, s);
        s = fmaf(qhi.z, khi.z, s);
        s = fmaf(qhi.w, khi.w, s);
        float p = __builtin_exp2f(s);
        l += p;
        a0.x = fmaf(p, klo.x, a0.x);
        a0.y = fmaf(p, klo.y, a0.y);
        a0.z = fmaf(p, klo.z, a0.z);
        a0.w = fmaf(p, klo.w, a0.w);
        a1.x = fmaf(p, khi.x, a1.x);
        a1.y = fmaf(p, khi.y, a1.y);
        a1.z = fmaf(p, khi.z, a1.z);
        a1.w = fmaf(p, khi.w, a1.w);
    }

    // ---- reduce partials across the 4 chunk-groups (reuse K4 LDS) ----
    __syncthreads();                       // all K4 reads done
    float* red = (float*)K4;               // (NCHUNK-1)*QBLK*9 floats = 13.5 KB
    if (chunk != 0) {
        int base = (tid - QBLK) * 9;       // stride 9: conflict-free (gcd(9,32)=1)
        red[base + 0] = a0.x; red[base + 1] = a0.y;
        red[base + 2] = a0.z; red[base + 3] = a0.w;
        red[base + 4] = a1.x; red[base + 5] = a1.y;
        red[base + 6] = a1.z; red[base + 7] = a1.w;
        red[base + 8] = l;
    }
    __syncthreads();
    if (chunk == 0) {
#pragma unroll
        for (int c = 0; c < NCHUNK - 1; ++c) {
            int base = (c * QBLK + row) * 9;
            a0.x += red[base + 0]; a0.y += red[base + 1];
            a0.z += red[base + 2]; a0.w += red[base + 3];
            a1.x += red[base + 4]; a1.y += red[base + 5];
            a1.z += red[base + 6]; a1.w += red[base + 7];
            l    += red[base + 8];
        }
        float inv = 1.0f / l;
        a0.x *= inv; a0.y *= inv; a0.z *= inv; a0.w *= inv;
        a1.x *= inv; a1.y *= inv; a1.z *= inv; a1.w *= inv;

        float4* o = (float4*)ws + ((size_t)(b * SEQ + qrow)) * (EMB / 4) + h * 2;
        o[0] = a0;
        o[1] = a1;
    }
}

// Kernel 2: out[r][e] = sum_k ws[r][k] * W[e][k]   (r = 0..4095, e,k = 0..127)
#define K2_ROWS 16
#define K2_THREADS 512
#define WT_STRIDE 132

__global__ __launch_bounds__(K2_THREADS) void combine_kernel(const float* __restrict__ ws,
                                                             const float* __restrict__ W,
                                                             float* __restrict__ out) {
    __shared__ float Wt[128 * WT_STRIDE];   // Wt[k*132 + e] = W[e][k]
    __shared__ float Xs[K2_ROWS * 128];

    const int tid   = threadIdx.x;
    const int rbase = blockIdx.x * K2_ROWS;

    for (int i = tid; i < 128 * 128; i += K2_THREADS) {
        int e = i >> 7, k = i & 127;        // coalesced global read
        Wt[k * WT_STRIDE + e] = W[i];
    }
    for (int i = tid; i < K2_ROWS * 128; i += K2_THREADS) {
        Xs[i] = ws[(size_t)rbase * 128 + i];
    }
    __syncthreads();

    const int r = tid >> 5;   // 0..15 (row within tile)
    const int g = tid & 31;   // column group: outputs e = 4g..4g+3
    float4 acc = make_float4(0.f, 0.f, 0.f, 0.f);

    const float4* X4 = (const float4*)&Xs[r * 128];
#pragma unroll
    for (int kc = 0; kc < 32; ++kc) {
        float4 x4 = X4[kc];  // broadcast within row group
#pragma unroll
        for (int j = 0; j < 4; ++j) {
            int k = kc * 4 + j;
            float4 w = *(const float4*)&Wt[k * WT_STRIDE + g * 4];
            float xv = (j == 0) ? x4.x : (j == 1) ? x4.y : (j == 2) ? x4.z : x4.w;
            acc.x = fmaf(xv, w.x, acc.x);
            acc.y = fmaf(xv, w.y, acc.y);
            acc.z = fmaf(xv, w.z, acc.z);
            acc.w = fmaf(xv, w.w, acc.w);
        }
    }

    ((float4*)out)[(size_t)(rbase + r) * 32 + g] = acc;
}

extern "C" void kernel_launch(void* const* d_in, const int* in_sizes, int n_in,
                              void* d_out, int out_size, void* d_ws, size_t ws_size,
                              hipStream_t stream) {
    const float* x     = (const float*)d_in[0];
    const float* theta = (const float*)d_in[1];
    const float* W     = (const float*)d_in[2];
    float* out = (float*)d_out;
    float* ws  = (float*)d_ws;   // needs B*S*E*4 = 2 MiB

    qattn_kernel<<<NBH * NQT, K1_THREADS, 0, stream>>>(x, theta, ws);
    combine_kernel<<<(NB * SEQ) / K2_ROWS, K2_THREADS, 0, stream>>>(ws, W, out);
}

// Round 7
// 46.300 us; speedup vs baseline: 1.7766x; 1.7741x over previous
//
#include <hip/hip_runtime.h>

#define SEQ   2048
#define EMB   128
#define NH    16
#define NB    2
#define NBH   (NB * NH)      // 32
#define QB    128            // q rows per block
#define NQB   (SEQ / QB)     // 16
#define K1_THREADS 512

typedef _Float16 half_t;
typedef _Float16 half4  __attribute__((ext_vector_type(4)));
typedef __fp16   fp16x2 __attribute__((ext_vector_type(2)));  // cvt_pkrtz return type
typedef float    floatx16 __attribute__((ext_vector_type(16)));

#define ZT_ROWS   10
#define ZT_STRIDE 2052   // halves; 4104 B/row: 8B-aligned, bank shift +2/row

// Kernel 1: MFMA flash attention, one (b,h) per block, q-range 128.
// Swapped QK^T (A=K, B=Q) so the score regs feed the PV A-operand directly.
// V gets a ones-column (d=8) so the softmax denominator falls out of the
// same MFMA; rows d=9..31 read the zero row / clamp, contributing 0.
__global__ __launch_bounds__(K1_THREADS, 4)
void qattn_mfma_kernel(const float* __restrict__ x,
                       const float* __restrict__ theta,
                       float* __restrict__ ws)
{
    __shared__ half4  zqk[2][SEQ];              // 32768 B: [hi][t] = z[t][4hi..4hi+3]
    __shared__ half_t zT[ZT_ROWS][ZT_STRIDE];   // 41040 B: [d][t], row8=1, row9=0

    const int tid = threadIdx.x;
    const int bid = blockIdx.x;
    const int bh  = bid >> 4;          // consecutive blocks share (b,h): L2-friendly
    const int qb  = bid & (NQB - 1);
    const int b   = bh >> 4;
    const int h   = bh & (NH - 1);

    float th[8];
#pragma unroll
    for (int d = 0; d < 8; ++d) th[d] = theta[d];

    const float4* x4 = (const float4*)x + (size_t)b * SEQ * (EMB / 4) + h * 2;

    // ---- stage z = cos(x+theta) as f16: row-major (zqk) + transposed (zT) ----
#pragma unroll
    for (int i = 0; i < SEQ / K1_THREADS; ++i) {
        const int t = tid + i * K1_THREADS;
        float4 lo  = x4[(size_t)t * (EMB / 4)];
        float4 hi4 = x4[(size_t)t * (EMB / 4) + 1];
        float z0 = __cosf(lo.x  + th[0]);
        float z1 = __cosf(lo.y  + th[1]);
        float z2 = __cosf(lo.z  + th[2]);
        float z3 = __cosf(lo.w  + th[3]);
        float z4 = __cosf(hi4.x + th[4]);
        float z5 = __cosf(hi4.y + th[5]);
        float z6 = __cosf(hi4.z + th[6]);
        float z7 = __cosf(hi4.w + th[7]);
        half4 zl, zh;
        zl[0] = (half_t)z0; zl[1] = (half_t)z1; zl[2] = (half_t)z2; zl[3] = (half_t)z3;
        zh[0] = (half_t)z4; zh[1] = (half_t)z5; zh[2] = (half_t)z6; zh[3] = (half_t)z7;
        zqk[0][t] = zl;
        zqk[1][t] = zh;
        zT[0][t] = zl[0]; zT[1][t] = zl[1]; zT[2][t] = zl[2]; zT[3][t] = zl[3];
        zT[4][t] = zh[0]; zT[5][t] = zh[1]; zT[6][t] = zh[2]; zT[7][t] = zh[3];
        zT[8][t] = (half_t)1.0f;   // ones column -> row-sum l
        zT[9][t] = (half_t)0.0f;   // zero row for clamped lanes d>8
    }
    __syncthreads();

    const int lane = tid & 63;
    const int wid  = tid >> 6;      // 0..7
    const int g    = wid & 3;       // q-tile (32 q) within block
    const int c    = wid >> 2;      // t-half (0: t<1024, 1: t>=1024)
    const int ln   = lane & 31;
    const int hi   = lane >> 5;

    // exp(s/sqrt(8)) = exp2(s * C); fold C into Q (f16 mul, |C*z|<=0.51)
    const float C = 0.35355339059327373f * 1.4426950408889634f;

    const half4* qk_base = &zqk[hi][0];
    half4 qf = qk_base[qb * QB + g * 32 + ln];
    qf = qf * (half_t)C;

    const half4* kp  = qk_base + ln;                  // kp[t0] = z[t0+ln][4hi..]
    const int    dcl = (ln < 9) ? ln : 9;
    const half4* vp  = (const half4*)((const char*)&zT[0][0] + dcl * (ZT_STRIDE * 2) + hi * 8);

    floatx16 acc = {};
    const floatx16 zero16 = {};
    const int tbase = c * (SEQ / 2);

#pragma unroll 4
    for (int tt = 0; tt < SEQ / 2; tt += 32) {
        const int t0 = tbase + tt;
        half4 kf = kp[t0];
        // s[t_local, q]: q = ln, t_local = (r&3)+8*(r>>2)+4*hi  (scaled scores)
        floatx16 s = __builtin_amdgcn_mfma_f32_32x32x8f16(kf, qf, zero16, 0, 0, 0);
        float p[16];
#pragma unroll
        for (int r = 0; r < 16; ++r) p[r] = __builtin_exp2f(s[r]);
#pragma unroll
        for (int w = 0; w < 4; ++w) {
            // PV A-frag for t-window w = regs 4w..4w+3 (derivation: reg = 4w+e)
            union { half4 h4; fp16x2 f2[2]; } u;
            u.f2[0] = __builtin_amdgcn_cvt_pkrtz(p[4 * w + 0], p[4 * w + 1]);
            u.f2[1] = __builtin_amdgcn_cvt_pkrtz(p[4 * w + 2], p[4 * w + 3]);
            half4 vf = vp[(t0 >> 2) + 2 * w];
            acc = __builtin_amdgcn_mfma_f32_32x32x8f16(u.h4, vf, acc, 0, 0, 0);
        }
    }

    // ---- combine t-halves (reuse zqk LDS), normalize, write ----
    __syncthreads();                        // all zqk/zT reads done
    float* red = (float*)&zqk[0][0];
    const int slot = (g * 64 + lane) * 17;  // stride 17: conflict-free
    if (c == 1) {
#pragma unroll
        for (int r = 0; r < 16; ++r) red[slot + r] = acc[r];
    }
    __syncthreads();
    if (c == 0) {
#pragma unroll
        for (int r = 0; r < 16; ++r) acc[r] += red[slot + r];

        // row-sum l sits in col 8 -> lane (8 | hi*32), same reg
#pragma unroll
        for (int r = 0; r < 16; ++r) {
            float lsum = __shfl(acc[r], 8 | (lane & 32), 64);
            acc[r] *= __builtin_amdgcn_rcpf(lsum);
        }

        if (ln < 8) {
            const int q0 = qb * QB + g * 32 + 4 * hi;
#pragma unroll
            for (int r = 0; r < 16; ++r) {
                const int q = q0 + (r & 3) + 8 * (r >> 2);
                ws[((size_t)(b * SEQ + q)) * EMB + h * 8 + ln] = acc[r];
            }
        }
    }
}

// Kernel 2: out[r][e] = sum_k ws[r][k] * W[e][k]
#define K2_ROWS 16
#define K2_THREADS 512
#define WT_STRIDE 132

__global__ __launch_bounds__(K2_THREADS) void combine_kernel(const float* __restrict__ ws,
                                                             const float* __restrict__ W,
                                                             float* __restrict__ out) {
    __shared__ float Wt[128 * WT_STRIDE];
    __shared__ float Xs[K2_ROWS * 128];

    const int tid   = threadIdx.x;
    const int rbase = blockIdx.x * K2_ROWS;

    for (int i = tid; i < 128 * 128; i += K2_THREADS) {
        int e = i >> 7, k = i & 127;
        Wt[k * WT_STRIDE + e] = W[i];
    }
    for (int i = tid; i < K2_ROWS * 128; i += K2_THREADS) {
        Xs[i] = ws[(size_t)rbase * 128 + i];
    }
    __syncthreads();

    const int r = tid >> 5;
    const int g = tid & 31;
    float4 acc = make_float4(0.f, 0.f, 0.f, 0.f);

    const float4* X4 = (const float4*)&Xs[r * 128];
#pragma unroll
    for (int kc = 0; kc < 32; ++kc) {
        float4 x4 = X4[kc];
#pragma unroll
        for (int j = 0; j < 4; ++j) {
            int k = kc * 4 + j;
            float4 w = *(const float4*)&Wt[k * WT_STRIDE + g * 4];
            float xv = (j == 0) ? x4.x : (j == 1) ? x4.y : (j == 2) ? x4.z : x4.w;
            acc.x = fmaf(xv, w.x, acc.x);
            acc.y = fmaf(xv, w.y, acc.y);
            acc.z = fmaf(xv, w.z, acc.z);
            acc.w = fmaf(xv, w.w, acc.w);
        }
    }

    ((float4*)out)[(size_t)(rbase + r) * 32 + g] = acc;
}

extern "C" void kernel_launch(void* const* d_in, const int* in_sizes, int n_in,
                              void* d_out, int out_size, void* d_ws, size_t ws_size,
                              hipStream_t stream) {
    const float* x     = (const float*)d_in[0];
    const float* theta = (const float*)d_in[1];
    const float* W     = (const float*)d_in[2];
    float* out = (float*)d_out;
    float* ws  = (float*)d_ws;   // B*S*E*4 = 2 MiB

    qattn_mfma_kernel<<<NBH * NQB, K1_THREADS, 0, stream>>>(x, theta, ws);
    combine_kernel<<<(NB * SEQ) / K2_ROWS, K2_THREADS, 0, stream>>>(ws, W, out);
}

// Round 8
// 30.162 us; speedup vs baseline: 2.7271x; 1.5351x over previous
//
#include <hip/hip_runtime.h>

#define SEQ   2048
#define EMB   128
#define NH    16
#define NB    2
#define NBH   (NB * NH)      // 32
#define QB    128            // q rows per block
#define NQB   (SEQ / QB)     // 16
#define K1_THREADS 512

typedef _Float16 half_t;
typedef _Float16 half4  __attribute__((ext_vector_type(4)));
typedef __fp16   fp16x2 __attribute__((ext_vector_type(2)));  // cvt_pkrtz return type
typedef float    floatx16 __attribute__((ext_vector_type(16)));

#define ZT_ROWS   10
#define ZT_STRIDE 2052   // halves; 4104 B/row: 8B-aligned, bank shift +2/row

// Kernel 1: MFMA flash attention, one (b,h) per block, q-range 128.
// Swapped QK^T (A=K, B=Q) so the score regs feed the PV A-operand directly.
// V gets a ones-column (d=8) so the softmax denominator falls out of the
// same MFMA; rows d=9..31 read the zero row / clamp, contributing 0.
__global__ __launch_bounds__(K1_THREADS, 4)
void qattn_mfma_kernel(const float* __restrict__ x,
                       const float* __restrict__ theta,
                       float* __restrict__ ws)
{
    __shared__ half4  zqk[2][SEQ];              // 32768 B: [hi][t] = z[t][4hi..4hi+3]
    __shared__ half_t zT[ZT_ROWS][ZT_STRIDE];   // 41040 B: [d][t], row8=1, row9=0

    const int tid = threadIdx.x;
    const int bid = blockIdx.x;
    const int bh  = bid >> 4;          // consecutive blocks share (b,h): L2-friendly
    const int qb  = bid & (NQB - 1);
    const int b   = bh >> 4;
    const int h   = bh & (NH - 1);

    float th[8];
#pragma unroll
    for (int d = 0; d < 8; ++d) th[d] = theta[d];

    const float4* x4 = (const float4*)x + (size_t)b * SEQ * (EMB / 4) + h * 2;

    // ---- stage z = cos(x+theta) as f16: row-major (zqk) + transposed (zT) ----
#pragma unroll
    for (int i = 0; i < SEQ / K1_THREADS; ++i) {
        const int t = tid + i * K1_THREADS;
        float4 lo  = x4[(size_t)t * (EMB / 4)];
        float4 hi4 = x4[(size_t)t * (EMB / 4) + 1];
        float z0 = __cosf(lo.x  + th[0]);
        float z1 = __cosf(lo.y  + th[1]);
        float z2 = __cosf(lo.z  + th[2]);
        float z3 = __cosf(lo.w  + th[3]);
        float z4 = __cosf(hi4.x + th[4]);
        float z5 = __cosf(hi4.y + th[5]);
        float z6 = __cosf(hi4.z + th[6]);
        float z7 = __cosf(hi4.w + th[7]);
        half4 zl, zh;
        zl[0] = (half_t)z0; zl[1] = (half_t)z1; zl[2] = (half_t)z2; zl[3] = (half_t)z3;
        zh[0] = (half_t)z4; zh[1] = (half_t)z5; zh[2] = (half_t)z6; zh[3] = (half_t)z7;
        zqk[0][t] = zl;
        zqk[1][t] = zh;
        zT[0][t] = zl[0]; zT[1][t] = zl[1]; zT[2][t] = zl[2]; zT[3][t] = zl[3];
        zT[4][t] = zh[0]; zT[5][t] = zh[1]; zT[6][t] = zh[2]; zT[7][t] = zh[3];
        zT[8][t] = (half_t)1.0f;   // ones column -> row-sum l
        zT[9][t] = (half_t)0.0f;   // zero row for clamped lanes d>8
    }
    __syncthreads();

    const int lane = tid & 63;
    const int wid  = tid >> 6;      // 0..7
    const int g    = wid & 3;       // q-tile (32 q) within block
    const int c    = wid >> 2;      // t-half (0: t<1024, 1: t>=1024)
    const int ln   = lane & 31;
    const int hi   = lane >> 5;

    // exp(s/sqrt(8)) = exp2(s * C); fold C into Q (f16 mul, |C*z|<=0.51)
    const float C = 0.35355339059327373f * 1.4426950408889634f;

    const half4* qk_base = &zqk[hi][0];
    half4 qf = qk_base[qb * QB + g * 32 + ln];
    qf = qf * (half_t)C;

    const half4* kp  = qk_base + ln;                  // kp[t0] = z[t0+ln][4hi..]
    const int    dcl = (ln < 9) ? ln : 9;
    const half4* vp  = (const half4*)((const char*)&zT[0][0] + dcl * (ZT_STRIDE * 2) + hi * 8);

    floatx16 acc0 = {};
    floatx16 acc1 = {};
    const floatx16 zero16 = {};
    const int tbase = c * (SEQ / 2);

#pragma unroll 4
    for (int tt = 0; tt < SEQ / 2; tt += 32) {
        const int t0 = tbase + tt;
        half4 kf = kp[t0];
        // s[t_local, q]: q = ln, t_local = (r&3)+8*(r>>2)+4*hi  (scaled scores)
        floatx16 s = __builtin_amdgcn_mfma_f32_32x32x8f16(kf, qf, zero16, 0, 0, 0);
        float p[16];
#pragma unroll
        for (int r = 0; r < 16; ++r) p[r] = __builtin_amdgcn_exp2f(s[r]);  // raw v_exp_f32
#pragma unroll
        for (int w = 0; w < 4; ++w) {
            // PV A-frag for t-window w = regs 4w..4w+3 (derivation: reg = 4w+e)
            union { half4 h4; fp16x2 f2[2]; } u;
            u.f2[0] = __builtin_amdgcn_cvt_pkrtz(p[4 * w + 0], p[4 * w + 1]);
            u.f2[1] = __builtin_amdgcn_cvt_pkrtz(p[4 * w + 2], p[4 * w + 3]);
            half4 vf = vp[(t0 >> 2) + 2 * w];
            if (w & 2)
                acc1 = __builtin_amdgcn_mfma_f32_32x32x8f16(u.h4, vf, acc1, 0, 0, 0);
            else
                acc0 = __builtin_amdgcn_mfma_f32_32x32x8f16(u.h4, vf, acc0, 0, 0, 0);
        }
    }

    floatx16 acc = acc0 + acc1;

    // ---- combine t-halves (reuse zqk LDS), normalize, write ----
    __syncthreads();                        // all zqk/zT reads done
    float* red = (float*)&zqk[0][0];
    const int slot = (g * 64 + lane) * 17;  // stride 17: conflict-free
    if (c == 1) {
#pragma unroll
        for (int r = 0; r < 16; ++r) red[slot + r] = acc[r];
    }
    __syncthreads();
    if (c == 0) {
#pragma unroll
        for (int r = 0; r < 16; ++r) acc[r] += red[slot + r];

        // row-sum l sits in col 8 -> lane (8 | hi*32), same reg
#pragma unroll
        for (int r = 0; r < 16; ++r) {
            float lsum = __shfl(acc[r], 8 | (lane & 32), 64);
            acc[r] *= __builtin_amdgcn_rcpf(lsum);
        }

        if (ln < 8) {
            const int q0 = qb * QB + g * 32 + 4 * hi;
#pragma unroll
            for (int r = 0; r < 16; ++r) {
                const int q = q0 + (r & 3) + 8 * (r >> 2);
                ws[((size_t)(b * SEQ + q)) * EMB + h * 8 + ln] = acc[r];
            }
        }
    }
}

// Kernel 2: out[r][e] = sum_k ws[r][k] * W[e][k]
#define K2_ROWS 16
#define K2_THREADS 512
#define WT_STRIDE 132

__global__ __launch_bounds__(K2_THREADS) void combine_kernel(const float* __restrict__ ws,
                                                             const float* __restrict__ W,
                                                             float* __restrict__ out) {
    __shared__ float Wt[128 * WT_STRIDE];
    __shared__ float Xs[K2_ROWS * 128];

    const int tid   = threadIdx.x;
    const int rbase = blockIdx.x * K2_ROWS;

    for (int i = tid; i < 128 * 128; i += K2_THREADS) {
        int e = i >> 7, k = i & 127;
        Wt[k * WT_STRIDE + e] = W[i];
    }
    for (int i = tid; i < K2_ROWS * 128; i += K2_THREADS) {
        Xs[i] = ws[(size_t)rbase * 128 + i];
    }
    __syncthreads();

    const int r = tid >> 5;
    const int g = tid & 31;
    float4 acc = make_float4(0.f, 0.f, 0.f, 0.f);

    const float4* X4 = (const float4*)&Xs[r * 128];
#pragma unroll
    for (int kc = 0; kc < 32; ++kc) {
        float4 x4 = X4[kc];
#pragma unroll
        for (int j = 0; j < 4; ++j) {
            int k = kc * 4 + j;
            float4 w = *(const float4*)&Wt[k * WT_STRIDE + g * 4];
            float xv = (j == 0) ? x4.x : (j == 1) ? x4.y : (j == 2) ? x4.z : x4.w;
            acc.x = fmaf(xv, w.x, acc.x);
            acc.y = fmaf(xv, w.y, acc.y);
            acc.z = fmaf(xv, w.z, acc.z);
            acc.w = fmaf(xv, w.w, acc.w);
        }
    }

    ((float4*)out)[(size_t)(rbase + r) * 32 + g] = acc;
}

extern "C" void kernel_launch(void* const* d_in, const int* in_sizes, int n_in,
                              void* d_out, int out_size, void* d_ws, size_t ws_size,
                              hipStream_t stream) {
    const float* x     = (const float*)d_in[0];
    const float* theta = (const float*)d_in[1];
    const float* W     = (const float*)d_in[2];
    float* out = (float*)d_out;
    float* ws  = (float*)d_ws;   // B*S*E*4 = 2 MiB

    qattn_mfma_kernel<<<NBH * NQB, K1_THREADS, 0, stream>>>(x, theta, ws);
    combine_kernel<<<(NB * SEQ) / K2_ROWS, K2_THREADS, 0, stream>>>(ws, W, out);
}

// Round 9
// 30.128 us; speedup vs baseline: 2.7302x; 1.0011x over previous
//
#include <hip/hip_runtime.h>

#define SEQ   2048
#define EMB   128
#define NH    16
#define NB    2
#define NBH   (NB * NH)      // 32
#define QB    128            // q rows per block
#define NQB   (SEQ / QB)     // 16
#define SEQ_H 1024           // tokens staged per block (one t-half)
#define K1_THREADS 512

typedef _Float16 half_t;
typedef _Float16 half4  __attribute__((ext_vector_type(4)));
typedef __fp16   fp16x2 __attribute__((ext_vector_type(2)));  // cvt_pkrtz return type
typedef float    floatx16 __attribute__((ext_vector_type(16)));

// LDS carve (aliased, 36944 B total -> 4 blocks/CU):
//   zqk  : half4 [2][1024]              @ 0      (16384 B)  row-major z, K-frags
//   zT   : 10 rows x 2056 B             @ 16384  (20560 B)  transposed z, V-frags
//          row d byte base = 16384 + d*2056 (shift 2 banks/row -> conflict-free)
//   red  : float[4352]                  @ 0      (alias, used after final sync)
#define SMEM_BYTES 36944
#define ZT_OFF     16384
#define ZT_PITCH   2056

// Kernel 1: MFMA flash attention partial. Block = (b,h,q-tile,t-half).
// Swapped QK^T (A=K, B=Q) so score regs feed the PV A-operand directly.
// V has a ones-column (d=8) so the row-sum l falls out of the same MFMA.
// Writes UNNORMALIZED partials: D-values (f16) to pD[row][c2][128] (d_out
// as scratch), row-sums (f32) to lbuf[row][c2*16+h] (ws).
__global__ __launch_bounds__(K1_THREADS, 8)
void qattn_mfma_kernel(const float* __restrict__ x,
                       const float* __restrict__ theta,
                       half_t* __restrict__ pD,
                       float* __restrict__ lbuf)
{
    __shared__ __align__(16) char smem[SMEM_BYTES];

    const int tid = threadIdx.x;
    const int bid = blockIdx.x;
    const int c2  = bid & 1;                 // t-half of the sequence
    const int qb  = (bid >> 1) & (NQB - 1);
    const int bh  = bid >> 5;                // 16 qb x 2 c2 blocks share (b,h)
    const int b   = bh >> 4;
    const int h   = bh & (NH - 1);

    float th[8];
#pragma unroll
    for (int d = 0; d < 8; ++d) th[d] = theta[d];

    const float4* x4 = (const float4*)x + (size_t)b * SEQ * (EMB / 4) + h * 2;

    half4* zqk0 = (half4*)smem;             // [t] = z[t][0..3]
    half4* zqk1 = (half4*)(smem + 8192);    // [t] = z[t][4..7]

    // ---- stage z = cos(x+theta) f16 for this t-half: row-major + transposed ----
#pragma unroll
    for (int i = 0; i < SEQ_H / K1_THREADS; ++i) {
        const int tl = tid + i * K1_THREADS;       // local token
        const int tg = c2 * SEQ_H + tl;            // global token
        float4 lo  = x4[(size_t)tg * (EMB / 4)];
        float4 hi4 = x4[(size_t)tg * (EMB / 4) + 1];
        float z0 = __cosf(lo.x  + th[0]);
        float z1 = __cosf(lo.y  + th[1]);
        float z2 = __cosf(lo.z  + th[2]);
        float z3 = __cosf(lo.w  + th[3]);
        float z4 = __cosf(hi4.x + th[4]);
        float z5 = __cosf(hi4.y + th[5]);
        float z6 = __cosf(hi4.z + th[6]);
        float z7 = __cosf(hi4.w + th[7]);
        half4 zl, zh;
        zl[0] = (half_t)z0; zl[1] = (half_t)z1; zl[2] = (half_t)z2; zl[3] = (half_t)z3;
        zh[0] = (half_t)z4; zh[1] = (half_t)z5; zh[2] = (half_t)z6; zh[3] = (half_t)z7;
        zqk0[tl] = zl;
        zqk1[tl] = zh;
#pragma unroll
        for (int d = 0; d < 4; ++d)
            *(half_t*)(smem + ZT_OFF + d * ZT_PITCH + tl * 2) = zl[d];
#pragma unroll
        for (int d = 0; d < 4; ++d)
            *(half_t*)(smem + ZT_OFF + (4 + d) * ZT_PITCH + tl * 2) = zh[d];
        *(half_t*)(smem + ZT_OFF + 8 * ZT_PITCH + tl * 2) = (half_t)1.0f;  // ones -> l
        *(half_t*)(smem + ZT_OFF + 9 * ZT_PITCH + tl * 2) = (half_t)0.0f;  // zero row
    }

    const int lane = tid & 63;
    const int wid  = tid >> 6;      // 0..7
    const int g    = wid & 3;       // q-tile (32 q) within block
    const int c    = wid >> 2;      // sub-half of this block's 1024 t
    const int ln   = lane & 31;
    const int hi   = lane >> 5;

    // Q from global (its token may live in the other t-half's staging).
    // exp(s/sqrt(8)) = exp2(s*C); fold C into Q (|C*z| <= 0.51, f16-safe)
    const float C = 0.35355339059327373f * 1.4426950408889634f;
    const int q = qb * QB + g * 32 + ln;
    float4 xq = ((const float4*)x)[(size_t)(b * SEQ + q) * (EMB / 4) + h * 2 + hi];
    half4 qf;
    qf[0] = (half_t)(__cosf(xq.x + th[4 * hi + 0]) * C);
    qf[1] = (half_t)(__cosf(xq.y + th[4 * hi + 1]) * C);
    qf[2] = (half_t)(__cosf(xq.z + th[4 * hi + 2]) * C);
    qf[3] = (half_t)(__cosf(xq.w + th[4 * hi + 3]) * C);

    __syncthreads();

    const half4* kp  = (hi ? zqk1 : zqk0) + ln;       // kp[t0] = z[t0+ln][4hi..]
    const int    dcl = (ln < 9) ? ln : 9;
    const half4* vp  = (const half4*)(smem + ZT_OFF + dcl * ZT_PITCH + hi * 8);

    floatx16 acc = {};
    const floatx16 zero16 = {};
    const int tb = c * (SEQ_H / 2);

#pragma unroll 4
    for (int tt = 0; tt < SEQ_H / 2; tt += 32) {
        const int t0 = tb + tt;
        half4 kf = kp[t0];
        // s[t_local, q]: q = ln, t_local = (r&3)+8*(r>>2)+4*hi  (scaled scores)
        floatx16 s = __builtin_amdgcn_mfma_f32_32x32x8f16(kf, qf, zero16, 0, 0, 0);
        float p[16];
#pragma unroll
        for (int r = 0; r < 16; ++r) p[r] = __builtin_amdgcn_exp2f(s[r]);
#pragma unroll
        for (int w = 0; w < 4; ++w) {
            // PV A-frag for t-window w = regs 4w..4w+3
            union { half4 h4; fp16x2 f2[2]; } u;
            u.f2[0] = __builtin_amdgcn_cvt_pkrtz(p[4 * w + 0], p[4 * w + 1]);
            u.f2[1] = __builtin_amdgcn_cvt_pkrtz(p[4 * w + 2], p[4 * w + 3]);
            half4 vf = vp[(t0 >> 2) + 2 * w];
            acc = __builtin_amdgcn_mfma_f32_32x32x8f16(u.h4, vf, acc, 0, 0, 0);
        }
    }

    // ---- combine the 2 sub-halves (LDS alias), write unnormalized partials ----
    __syncthreads();                        // all zqk/zT reads done
    float* red = (float*)smem;
    const int slot = (g * 64 + lane) * 17;  // stride 17: conflict-free
    if (c == 1) {
#pragma unroll
        for (int r = 0; r < 16; ++r) red[slot + r] = acc[r];
    }
    __syncthreads();
    if (c == 0) {
#pragma unroll
        for (int r = 0; r < 16; ++r) acc[r] += red[slot + r];

        const int q0 = qb * QB + g * 32 + 4 * hi;
        if (ln < 8) {
#pragma unroll
            for (int r = 0; r < 16; ++r) {
                const int qq = q0 + (r & 3) + 8 * (r >> 2);
                pD[((size_t)(b * SEQ + qq) * 2 + c2) * EMB + h * 8 + ln] = (half_t)acc[r];
            }
        } else if (ln == 8) {
#pragma unroll
            for (int r = 0; r < 16; ++r) {
                const int qq = q0 + (r & 3) + 8 * (r >> 2);
                lbuf[(size_t)(b * SEQ + qq) * 32 + c2 * 16 + h] = acc[r];
            }
        }
    }
}

// Kernel 2: sum t-half partials, normalize, then out[r][e] = sum_k X[r][k]*W[e][k].
// pD aliases out (per-row layout: row r's partials live in row r's out bytes,
// read fully before the block's own writes -> no cross-block race).
#define K2_ROWS 16
#define K2_THREADS 512
#define WT_STRIDE 132

__global__ __launch_bounds__(K2_THREADS) void combine_kernel(const half_t* pD,
                                                             const float* __restrict__ lbuf,
                                                             const float* __restrict__ W,
                                                             float* out) {
    __shared__ float Wt[128 * WT_STRIDE];
    __shared__ float Xs[K2_ROWS * 128];

    const int tid   = threadIdx.x;
    const int rbase = blockIdx.x * K2_ROWS;

    for (int i = tid; i < 128 * 128; i += K2_THREADS) {
        int e = i >> 7, k = i & 127;
        Wt[k * WT_STRIDE + e] = W[i];
    }
#pragma unroll
    for (int j = 0; j < (K2_ROWS * 128) / K2_THREADS; ++j) {
        const int i = tid + j * K2_THREADS;
        const int r = i >> 7, k = i & 127, hh = k >> 3;
        const int row = rbase + r;
        float p = (float)pD[(size_t)row * 256 + k] + (float)pD[(size_t)row * 256 + 128 + k];
        float l = lbuf[(size_t)row * 32 + hh] + lbuf[(size_t)row * 32 + 16 + hh];
        Xs[i] = p * __builtin_amdgcn_rcpf(l);
    }
    __syncthreads();

    const int r = tid >> 5;
    const int g = tid & 31;
    float4 acc = make_float4(0.f, 0.f, 0.f, 0.f);

    const float4* X4 = (const float4*)&Xs[r * 128];
#pragma unroll
    for (int kc = 0; kc < 32; ++kc) {
        float4 x4 = X4[kc];
#pragma unroll
        for (int j = 0; j < 4; ++j) {
            int k = kc * 4 + j;
            float4 w = *(const float4*)&Wt[k * WT_STRIDE + g * 4];
            float xv = (j == 0) ? x4.x : (j == 1) ? x4.y : (j == 2) ? x4.z : x4.w;
            acc.x = fmaf(xv, w.x, acc.x);
            acc.y = fmaf(xv, w.y, acc.y);
            acc.z = fmaf(xv, w.z, acc.z);
            acc.w = fmaf(xv, w.w, acc.w);
        }
    }

    ((float4*)out)[(size_t)(rbase + r) * 32 + g] = acc;
}

extern "C" void kernel_launch(void* const* d_in, const int* in_sizes, int n_in,
                              void* d_out, int out_size, void* d_ws, size_t ws_size,
                              hipStream_t stream) {
    const float* x     = (const float*)d_in[0];
    const float* theta = (const float*)d_in[1];
    const float* W     = (const float*)d_in[2];
    float*  out  = (float*)d_out;
    half_t* pD   = (half_t*)d_out;   // d_out doubles as f16 partial scratch
    float*  lbuf = (float*)d_ws;     // 512 KiB row-sum partials

    qattn_mfma_kernel<<<NBH * NQB * 2, K1_THREADS, 0, stream>>>(x, theta, pD, lbuf);
    combine_kernel<<<(NB * SEQ) / K2_ROWS, K2_THREADS, 0, stream>>>(pD, lbuf, W, out);
}

// Round 10
// 28.068 us; speedup vs baseline: 2.9306x; 1.0734x over previous
//
#include <hip/hip_runtime.h>

#define SEQ   2048
#define EMB   128
#define NH    16
#define NB    2
#define NBH   (NB * NH)      // 32
#define QB    128            // q rows per block
#define NQB   (SEQ / QB)     // 16
#define SEQ_H 1024           // tokens staged per block (one t-half)
#define K1_THREADS 512

typedef _Float16 half_t;
typedef _Float16 half4  __attribute__((ext_vector_type(4)));
typedef __fp16   fp16x2 __attribute__((ext_vector_type(2)));  // cvt_pkrtz return type
typedef float    floatx16 __attribute__((ext_vector_type(16)));

// LDS carve (aliased, 36944 B total -> 4 blocks/CU):
//   zqk  : half4 [2][1024]              @ 0      (16384 B)  row-major z, K-frags
//   zT   : 10 rows x 2056 B             @ 16384  (20560 B)  transposed z, V-frags
//   red  : float[4352]                  @ 0      (alias, used after final sync)
#define SMEM_BYTES 36944
#define ZT_OFF     16384
#define ZT_PITCH   2056

// Kernel 1: MFMA flash attention partial. Block = (b,h,q-tile,t-half).
// Swapped QK^T (A=K, B=Q) so score regs feed the PV A-operand directly.
// V has a ones-column (d=8) so the row-sum l falls out of the same MFMA.
// Writes UNNORMALIZED partials: D-values (f16) to pD[row][c2][128] (d_out
// as scratch), row-sums (f32) to lbuf[row][c2*16+h] (ws).
__global__ __launch_bounds__(K1_THREADS, 8)
void qattn_mfma_kernel(const float* __restrict__ x,
                       const float* __restrict__ theta,
                       half_t* __restrict__ pD,
                       float* __restrict__ lbuf)
{
    __shared__ __align__(16) char smem[SMEM_BYTES];

    const int tid = threadIdx.x;
    const int bid = blockIdx.x;
    const int c2  = bid & 1;                 // t-half of the sequence
    const int qb  = (bid >> 1) & (NQB - 1);
    const int bh  = bid >> 5;                // 16 qb x 2 c2 blocks share (b,h)
    const int b   = bh >> 4;
    const int h   = bh & (NH - 1);

    float th[8];
#pragma unroll
    for (int d = 0; d < 8; ++d) th[d] = theta[d];

    const float4* x4 = (const float4*)x + (size_t)b * SEQ * (EMB / 4) + h * 2;

    half4* zqk0 = (half4*)smem;             // [t] = z[t][0..3]
    half4* zqk1 = (half4*)(smem + 8192);    // [t] = z[t][4..7]

    // ---- stage z = cos(x+theta) f16 for this t-half: row-major + transposed ----
#pragma unroll
    for (int i = 0; i < SEQ_H / K1_THREADS; ++i) {
        const int tl = tid + i * K1_THREADS;       // local token
        const int tg = c2 * SEQ_H + tl;            // global token
        float4 lo  = x4[(size_t)tg * (EMB / 4)];
        float4 hi4 = x4[(size_t)tg * (EMB / 4) + 1];
        float z0 = __cosf(lo.x  + th[0]);
        float z1 = __cosf(lo.y  + th[1]);
        float z2 = __cosf(lo.z  + th[2]);
        float z3 = __cosf(lo.w  + th[3]);
        float z4 = __cosf(hi4.x + th[4]);
        float z5 = __cosf(hi4.y + th[5]);
        float z6 = __cosf(hi4.z + th[6]);
        float z7 = __cosf(hi4.w + th[7]);
        half4 zl, zh;
        zl[0] = (half_t)z0; zl[1] = (half_t)z1; zl[2] = (half_t)z2; zl[3] = (half_t)z3;
        zh[0] = (half_t)z4; zh[1] = (half_t)z5; zh[2] = (half_t)z6; zh[3] = (half_t)z7;
        zqk0[tl] = zl;
        zqk1[tl] = zh;
#pragma unroll
        for (int d = 0; d < 4; ++d)
            *(half_t*)(smem + ZT_OFF + d * ZT_PITCH + tl * 2) = zl[d];
#pragma unroll
        for (int d = 0; d < 4; ++d)
            *(half_t*)(smem + ZT_OFF + (4 + d) * ZT_PITCH + tl * 2) = zh[d];
        *(half_t*)(smem + ZT_OFF + 8 * ZT_PITCH + tl * 2) = (half_t)1.0f;  // ones -> l
        *(half_t*)(smem + ZT_OFF + 9 * ZT_PITCH + tl * 2) = (half_t)0.0f;  // zero row
    }

    const int lane = tid & 63;
    const int wid  = tid >> 6;      // 0..7
    const int g    = wid & 3;       // q-tile (32 q) within block
    const int c    = wid >> 2;      // sub-half of this block's 1024 t
    const int ln   = lane & 31;
    const int hi   = lane >> 5;

    // Q from global (its token may live in the other t-half's staging).
    // exp(s/sqrt(8)) = exp2(s*C); fold C into Q (|C*z| <= 0.51, f16-safe)
    const float C = 0.35355339059327373f * 1.4426950408889634f;
    const int q = qb * QB + g * 32 + ln;
    float4 xq = ((const float4*)x)[(size_t)(b * SEQ + q) * (EMB / 4) + h * 2 + hi];
    half4 qf;
    qf[0] = (half_t)(__cosf(xq.x + th[4 * hi + 0]) * C);
    qf[1] = (half_t)(__cosf(xq.y + th[4 * hi + 1]) * C);
    qf[2] = (half_t)(__cosf(xq.z + th[4 * hi + 2]) * C);
    qf[3] = (half_t)(__cosf(xq.w + th[4 * hi + 3]) * C);

    __syncthreads();

    const half4* kp  = (hi ? zqk1 : zqk0) + ln;       // kp[t0] = z[t0+ln][4hi..]
    const int    dcl = (ln < 9) ? ln : 9;
    const half4* vp  = (const half4*)(smem + ZT_OFF + dcl * ZT_PITCH + hi * 8);

    floatx16 acc = {};
    const floatx16 zero16 = {};
    const int tb = c * (SEQ_H / 2);

#pragma unroll 4
    for (int tt = 0; tt < SEQ_H / 2; tt += 32) {
        const int t0 = tb + tt;
        half4 kf = kp[t0];
        // s[t_local, q]: q = ln, t_local = (r&3)+8*(r>>2)+4*hi  (scaled scores)
        floatx16 s = __builtin_amdgcn_mfma_f32_32x32x8f16(kf, qf, zero16, 0, 0, 0);
        float p[16];
#pragma unroll
        for (int r = 0; r < 16; ++r) p[r] = __builtin_amdgcn_exp2f(s[r]);
#pragma unroll
        for (int w = 0; w < 4; ++w) {
            // PV A-frag for t-window w = regs 4w..4w+3
            union { half4 h4; fp16x2 f2[2]; } u;
            u.f2[0] = __builtin_amdgcn_cvt_pkrtz(p[4 * w + 0], p[4 * w + 1]);
            u.f2[1] = __builtin_amdgcn_cvt_pkrtz(p[4 * w + 2], p[4 * w + 3]);
            half4 vf = vp[(t0 >> 2) + 2 * w];
            acc = __builtin_amdgcn_mfma_f32_32x32x8f16(u.h4, vf, acc, 0, 0, 0);
        }
    }

    // ---- combine the 2 sub-halves (LDS alias), write unnormalized partials ----
    __syncthreads();                        // all zqk/zT reads done
    float* red = (float*)smem;
    const int slot = (g * 64 + lane) * 17;  // stride 17: conflict-free
    if (c == 1) {
#pragma unroll
        for (int r = 0; r < 16; ++r) red[slot + r] = acc[r];
    }
    __syncthreads();
    if (c == 0) {
#pragma unroll
        for (int r = 0; r < 16; ++r) acc[r] += red[slot + r];

        const int q0 = qb * QB + g * 32 + 4 * hi;
        if (ln < 8) {
#pragma unroll
            for (int r = 0; r < 16; ++r) {
                const int qq = q0 + (r & 3) + 8 * (r >> 2);
                pD[((size_t)(b * SEQ + qq) * 2 + c2) * EMB + h * 8 + ln] = (half_t)acc[r];
            }
        } else if (ln == 8) {
#pragma unroll
            for (int r = 0; r < 16; ++r) {
                const int qq = q0 + (r & 3) + 8 * (r >> 2);
                lbuf[(size_t)(b * SEQ + qq) * 32 + c2 * 16 + h] = acc[r];
            }
        }
    }
}

// Kernel 2 (MFMA): sum t-half partials, normalize -> Xn f16; W -> f16; then
// out[r][e] = sum_k Xn[r][k] W[e][k] via 32x32x8 f16 MFMA.
// A-frag = Xn rows (lane=row), B-frag = W (lane=e, b[k]=W[e][k]) so D rows are
// r and cols are e -> coalesced stores. LDS pitch 132 halves (264 B) = 2-bank
// shift per row -> conflict-free ds_read_b64 frags.
// pD aliases out per-row (row r's partials live in row r's out bytes; all
// reads complete before this block's writes; blocks touch only their rows).
#define K2_ROWS    32
#define K2_THREADS 256
#define XW_PITCH   132

__global__ __launch_bounds__(K2_THREADS)
void combine_mfma_kernel(const half_t* pD,
                         const float* __restrict__ lbuf,
                         const float* __restrict__ W,
                         float* out)
{
    __shared__ half_t Ws[128 * XW_PITCH];      // [e][k] f16, 33792 B
    __shared__ half_t Xs[K2_ROWS * XW_PITCH];  // [r][k] f16 normalized, 8448 B

    const int tid   = threadIdx.x;
    const int rbase = blockIdx.x * K2_ROWS;

    // ---- stage W as f16 ----
#pragma unroll
    for (int it = 0; it < 16; ++it) {
        const int idx = tid + it * K2_THREADS;   // 0..4095 float4s
        const int e   = idx >> 5;
        const int k4  = idx & 31;
        float4 w = ((const float4*)W)[idx];
        union { half4 h4; fp16x2 f2[2]; } u;
        u.f2[0] = __builtin_amdgcn_cvt_pkrtz(w.x, w.y);
        u.f2[1] = __builtin_amdgcn_cvt_pkrtz(w.z, w.w);
        *(half4*)&Ws[e * XW_PITCH + 4 * k4] = u.h4;
    }
    // ---- stage Xn = (pD_half0 + pD_half1) / l as f16 ----
#pragma unroll
    for (int it = 0; it < 8; ++it) {
        const int idx = tid + it * K2_THREADS;   // 0..2047: (r, k2)
        const int r   = idx >> 6;
        const int k2  = idx & 63;                // k = 2*k2
        const int row = rbase + r;
        const half_t* p0 = &pD[(size_t)row * 256 + 2 * k2];
        const int hh = k2 >> 2;
        float l  = lbuf[(size_t)row * 32 + hh] + lbuf[(size_t)row * 32 + 16 + hh];
        float rl = __builtin_amdgcn_rcpf(l);
        float v0 = ((float)p0[0] + (float)p0[128]) * rl;
        float v1 = ((float)p0[1] + (float)p0[129]) * rl;
        *(fp16x2*)&Xs[r * XW_PITCH + 2 * k2] = __builtin_amdgcn_cvt_pkrtz(v0, v1);
    }
    __syncthreads();

    const int lane = tid & 63;
    const int wv   = tid >> 6;     // 0..3 -> e-tile
    const int ln   = lane & 31;
    const int hi   = lane >> 5;
    const int e0   = wv * 32;

    floatx16 acc = {};
#pragma unroll
    for (int kk = 0; kk < 16; ++kk) {
        half4 a = *(const half4*)&Xs[ln * XW_PITCH + kk * 8 + hi * 4];          // X[r=ln][k..]
        half4 bf = *(const half4*)&Ws[(e0 + ln) * XW_PITCH + kk * 8 + hi * 4];  // W[e=ln][k..]
        acc = __builtin_amdgcn_mfma_f32_32x32x8f16(a, bf, acc, 0, 0, 0);
    }

    // D: col = e0+ln, row r_loc = (reg&3)+8*(reg>>2)+4*hi -> coalesced stores
#pragma unroll
    for (int reg = 0; reg < 16; ++reg) {
        const int r_loc = (reg & 3) + 8 * (reg >> 2) + 4 * hi;
        out[(size_t)(rbase + r_loc) * EMB + e0 + ln] = acc[reg];
    }
}

extern "C" void kernel_launch(void* const* d_in, const int* in_sizes, int n_in,
                              void* d_out, int out_size, void* d_ws, size_t ws_size,
                              hipStream_t stream) {
    const float* x     = (const float*)d_in[0];
    const float* theta = (const float*)d_in[1];
    const float* W     = (const float*)d_in[2];
    float*  out  = (float*)d_out;
    half_t* pD   = (half_t*)d_out;   // d_out doubles as f16 partial scratch
    float*  lbuf = (float*)d_ws;     // 512 KiB row-sum partials

    qattn_mfma_kernel<<<NBH * NQB * 2, K1_THREADS, 0, stream>>>(x, theta, pD, lbuf);
    combine_mfma_kernel<<<(NB * SEQ) / K2_ROWS, K2_THREADS, 0, stream>>>(pD, lbuf, W, out);
}